// Round 1
// baseline (967.479 us; speedup 1.0000x reference)
//
#include <hip/hip_runtime.h>

#define Nn 10000
#define Ee 160000
#define HID 256
#define EDIM 9
#define INDIM 10
#define Tt 5

typedef _Float16 f16;
typedef _Float16 f16x8 __attribute__((ext_vector_type(8)));
typedef float f32x4 __attribute__((ext_vector_type(4)));

// ---------------- edge-attr column stats (mean / sumsq) ----------------
__global__ __launch_bounds__(256) void colstats_kernel(const float* __restrict__ in,
                                                       float* __restrict__ cs) {
  float s[9], s2[9];
#pragma unroll
  for (int k = 0; k < 9; ++k) { s[k] = 0.f; s2[k] = 0.f; }
  for (int i = blockIdx.x * blockDim.x + threadIdx.x; i < Ee; i += gridDim.x * blockDim.x) {
#pragma unroll
    for (int k = 0; k < 9; ++k) {
      float v = in[i * 9 + k];
      s[k] += v; s2[k] += v * v;
    }
  }
#pragma unroll
  for (int k = 0; k < 9; ++k) {
    for (int off = 1; off < 64; off <<= 1) {
      s[k] += __shfl_xor(s[k], off);
      s2[k] += __shfl_xor(s2[k], off);
    }
  }
  if ((threadIdx.x & 63) == 0) {
#pragma unroll
    for (int k = 0; k < 9; ++k) {
      atomicAdd(&cs[k], s[k]);
      atomicAdd(&cs[16 + k], s2[k]);
    }
  }
}

__global__ __launch_bounds__(256) void eanorm_kernel(const float* __restrict__ in,
                                                     const float* __restrict__ cs,
                                                     float* __restrict__ ea) {
  int idx = blockIdx.x * 256 + threadIdx.x;
  if (idx >= Ee * 9) return;
  int c = idx % 9;
  float mu = cs[c] * (1.f / Ee);
  float var = fmaxf(cs[16 + c] * (1.f / Ee) - mu * mu, 0.f);
  float sd = sqrtf(var) + 1e-8f;   // jnp.std (biased) + 1e-8
  ea[idx] = (in[idx] - mu) / sd;
}

// ---------------- lift: h = relu(x @ lift_W + b), stored fp16 ----------------
__global__ __launch_bounds__(256) void lift_kernel(const float* __restrict__ x,
                                                   const float* __restrict__ W,
                                                   const float* __restrict__ b,
                                                   f16* __restrict__ hq) {
  __shared__ float xs[INDIM];
  int n = blockIdx.x, ch = threadIdx.x;
  if (ch < INDIM) xs[ch] = x[n * INDIM + ch];
  __syncthreads();
  float s = b[ch];
#pragma unroll
  for (int k = 0; k < INDIM; ++k) s += xs[k] * W[k * 256 + ch];
  hq[n * 256 + ch] = (f16)fmaxf(s, 0.f);
}

// ---------------- CSR build (by destination) ----------------
__global__ __launch_bounds__(256) void degree_kernel(const int* __restrict__ dst,
                                                     int* __restrict__ deg) {
  int e = blockIdx.x * 256 + threadIdx.x;
  if (e < Ee) atomicAdd(&deg[dst[e]], 1);
}

__global__ __launch_bounds__(1024) void scan_kernel(const int* __restrict__ deg,
                                                    int* __restrict__ rowptr,
                                                    int* __restrict__ cursor) {
  __shared__ int part[1024];
  int tid = threadIdx.x;
  const int CH = (Nn + 1023) / 1024;
  int start = tid * CH;
  int s = 0;
  for (int i = 0; i < CH; ++i) { int idx = start + i; if (idx < Nn) s += deg[idx]; }
  part[tid] = s;
  __syncthreads();
  for (int off = 1; off < 1024; off <<= 1) {
    int v = part[tid];
    int w = (tid >= off) ? part[tid - off] : 0;
    __syncthreads();
    part[tid] = v + w;
    __syncthreads();
  }
  int run = part[tid] - s;  // exclusive prefix
  for (int i = 0; i < CH; ++i) {
    int idx = start + i;
    if (idx < Nn) { rowptr[idx] = run; cursor[idx] = run; run += deg[idx]; }
  }
  if (tid == 0) rowptr[Nn] = Ee;
}

__global__ __launch_bounds__(256) void fill_kernel(const int* __restrict__ dst,
                                                   int* __restrict__ cursor,
                                                   int* __restrict__ perm) {
  int e = blockIdx.x * 256 + threadIdx.x;
  if (e < Ee) {
    int pos = atomicAdd(&cursor[dst[e]], 1);
    perm[pos] = e;
  }
}

// ---------------- weight convert: fp32 [256k,256n] -> fp16 transposed [n][k] ----------------
__global__ __launch_bounds__(256) void convert_kernel(const float* __restrict__ Wl,
                                                      const float* __restrict__ Wr,
                                                      const float* __restrict__ p1,
                                                      const float* __restrict__ p2,
                                                      f16* __restrict__ wt) {
  int nrow = blockIdx.x, s = blockIdx.y, k = threadIdx.x;
  const float* srcp;
  if (s < 5) srcp = Wl + s * 65536;
  else if (s < 10) srcp = Wr + (s - 5) * 65536;
  else if (s == 10) srcp = p1;
  else srcp = p2;
  wt[s * 65536 + nrow * 256 + k] = (f16)srcp[k * 256 + nrow];
}

// ---------------- fp16 MFMA GEMM: C[M,256] = A[M,256] @ B + bias (B given transposed) ----------------
__global__ __launch_bounds__(256) void gemm16_kernel(const f16* __restrict__ A,
                                                     const f16* __restrict__ BT,
                                                     const float* __restrict__ bias,
                                                     float* __restrict__ Cmat, int M) {
  __shared__ __align__(16) f16 As[64][40];
  __shared__ __align__(16) f16 Bs[64][40];
  const int tid = threadIdx.x;
  const int wave = tid >> 6, lane = tid & 63;
  const int l15 = lane & 15, quad = lane >> 4;
  const int m0 = blockIdx.x * 64, n0 = blockIdx.y * 64;
  const int wm = (wave >> 1) * 32, wn = (wave & 1) * 32;
  f32x4 zero4 = {0.f, 0.f, 0.f, 0.f};
  f32x4 acc[2][2] = {{zero4, zero4}, {zero4, zero4}};
  const int row = tid >> 2, k8 = (tid & 3) << 3;
  for (int kk = 0; kk < 256; kk += 32) {
    f16x8 av;
#pragma unroll
    for (int z = 0; z < 8; ++z) av[z] = (f16)0.f;
    int gm = m0 + row;
    if (gm < M) av = *(const f16x8*)(A + gm * 256 + kk + k8);
    f16x8 bv = *(const f16x8*)(BT + (n0 + row) * 256 + kk + k8);
    __syncthreads();
    *(f16x8*)(&As[row][k8]) = av;
    *(f16x8*)(&Bs[row][k8]) = bv;
    __syncthreads();
    // A frag: A[m=lane&15][k=quad*8+j]; B frag from BT rows: B[n=lane&15][k=quad*8+j]
    f16x8 a0 = *(const f16x8*)(&As[wm + l15][quad * 8]);
    f16x8 a1 = *(const f16x8*)(&As[wm + 16 + l15][quad * 8]);
    f16x8 b0 = *(const f16x8*)(&Bs[wn + l15][quad * 8]);
    f16x8 b1 = *(const f16x8*)(&Bs[wn + 16 + l15][quad * 8]);
    acc[0][0] = __builtin_amdgcn_mfma_f32_16x16x32_f16(a0, b0, acc[0][0], 0, 0, 0);
    acc[0][1] = __builtin_amdgcn_mfma_f32_16x16x32_f16(a0, b1, acc[0][1], 0, 0, 0);
    acc[1][0] = __builtin_amdgcn_mfma_f32_16x16x32_f16(a1, b0, acc[1][0], 0, 0, 0);
    acc[1][1] = __builtin_amdgcn_mfma_f32_16x16x32_f16(a1, b1, acc[1][1], 0, 0, 0);
  }
  // C/D layout: col = lane&15, row = quad*4 + reg
#pragma unroll
  for (int mi = 0; mi < 2; ++mi)
#pragma unroll
    for (int ni = 0; ni < 2; ++ni) {
      int nG = n0 + wn + ni * 16 + l15;
      float bv2 = bias[nG];
#pragma unroll
      for (int r = 0; r < 4; ++r) {
        int mG = m0 + wm + mi * 16 + quad * 4 + r;
        if (mG < M) Cmat[mG * 256 + nG] = acc[mi][ni][r] + bv2;
      }
    }
}

// ---------------- GATv2 edge+softmax+aggregate: one wave per node, online softmax ----------------
__global__ __launch_bounds__(256) void gat_kernel(const float* __restrict__ xl,
                                                  const float* __restrict__ xr,
                                                  const float* __restrict__ ea,
                                                  const int* __restrict__ src,
                                                  const int* __restrict__ rowptr,
                                                  const int* __restrict__ perm,
                                                  const float* __restrict__ We_t,
                                                  const float* __restrict__ att_t,
                                                  const float* __restrict__ cb_t,
                                                  float* __restrict__ outb) {
  int wave = threadIdx.x >> 6, lane = threadIdx.x & 63;
  int i = blockIdx.x * 4 + wave;
  if (i >= Nn) return;
  int ch = lane * 4;  // lane owns flat channels [4*lane, 4*lane+4): head = lane>>3
  float we[9][4];
#pragma unroll
  for (int k = 0; k < 9; ++k) {
    float4 w4 = *(const float4*)(We_t + k * 256 + ch);
    we[k][0] = w4.x; we[k][1] = w4.y; we[k][2] = w4.z; we[k][3] = w4.w;
  }
  float4 a4 = *(const float4*)(att_t + ch);
  float att[4] = {a4.x, a4.y, a4.z, a4.w};
  float4 x4 = *(const float4*)(xr + i * 256 + ch);
  float xri[4] = {x4.x, x4.y, x4.z, x4.w};
  float m = -INFINITY, l = 0.f;
  float acc[4] = {0.f, 0.f, 0.f, 0.f};
  int r0 = rowptr[i], r1 = rowptr[i + 1];
  for (int idx = r0; idx < r1; ++idx) {
    int e = perm[idx];
    int j = src[e];
    float4 xl4 = *(const float4*)(xl + j * 256 + ch);
    float xlv[4] = {xl4.x, xl4.y, xl4.z, xl4.w};
    const float* eap = ea + e * 9;
    float v[4];
#pragma unroll
    for (int c = 0; c < 4; ++c) v[c] = xlv[c] + xri[c];
#pragma unroll
    for (int k = 0; k < 9; ++k) {
      float ek = eap[k];
#pragma unroll
      for (int c = 0; c < 4; ++c) v[c] += ek * we[k][c];
    }
    float sp = 0.f;
#pragma unroll
    for (int c = 0; c < 4; ++c) {
      float vv = v[c];
      vv = vv > 0.f ? vv : 0.2f * vv;  // leaky_relu 0.2
      sp += att[c] * vv;
    }
    // reduce over the 8 lanes of this head
    sp += __shfl_xor(sp, 1);
    sp += __shfl_xor(sp, 2);
    sp += __shfl_xor(sp, 4);
    float nm = fmaxf(m, sp);
    float sc = __expf(m - nm);   // exp(-inf)=0 handles first edge
    float p = __expf(sp - nm);
    l = l * sc + p;
#pragma unroll
    for (int c = 0; c < 4; ++c) acc[c] = acc[c] * sc + p * xlv[c];
    m = nm;
  }
  float4 cb4 = *(const float4*)(cb_t + ch);
  float inv = 1.f / (l + 1e-16f);  // matches z/(denom+1e-16); empty node -> bias only
  float4 o;
  o.x = acc[0] * inv + cb4.x;
  o.y = acc[1] * inv + cb4.y;
  o.z = acc[2] * inv + cb4.z;
  o.w = acc[3] * inv + cb4.w;
  *(float4*)(outb + i * 256 + ch) = o;
}

// ---------------- BatchNorm batch-stats + apply(+act) with fp16 downcast ----------------
__global__ __launch_bounds__(256) void bn_stats_kernel(const float* __restrict__ v,
                                                       float* __restrict__ sums) {
  int ch = threadIdx.x;
  float s = 0.f, s2 = 0.f;
  for (int n = blockIdx.x; n < Nn; n += gridDim.x) {
    float x = v[n * 256 + ch];
    s += x; s2 += x * x;
  }
  atomicAdd(&sums[ch], s);
  atomicAdd(&sums[256 + ch], s2);
}

__global__ __launch_bounds__(256) void bn_apply_kernel(const float* __restrict__ v,
                                                       const float* __restrict__ sums,
                                                       const float* __restrict__ gamma,
                                                       const float* __restrict__ beta,
                                                       f16* __restrict__ hq, int act) {
  int idx = blockIdx.x * 256 + threadIdx.x;
  int ch = idx & 255;
  float mu = sums[ch] * (1.f / Nn);
  float var = fmaxf(sums[256 + ch] * (1.f / Nn) - mu * mu, 0.f);  // biased var
  float inv = rsqrtf(var + 1e-5f);
  float y = gamma[ch] * (v[idx] - mu) * inv + beta[ch];
  if (act == 0) y = y > 0.f ? y : (__expf(y) - 1.f);  // ELU
  else y = fmaxf(y, 0.f);                             // ReLU
  hq[idx] = (f16)y;
}

// ---------------- final 256 -> 3 projection ----------------
__global__ __launch_bounds__(64) void final_kernel(const f16* __restrict__ hq,
                                                   const float* __restrict__ W,
                                                   const float* __restrict__ b,
                                                   float* __restrict__ out3) {
  int n = blockIdx.x, lane = threadIdx.x;
  int ch = lane * 4;
  float s0 = 0.f, s1 = 0.f, s2 = 0.f;
#pragma unroll
  for (int c2 = 0; c2 < 4; ++c2) {
    float h = (float)hq[n * 256 + ch + c2];
    const float* w = W + (ch + c2) * 3;
    s0 += h * w[0]; s1 += h * w[1]; s2 += h * w[2];
  }
  for (int off = 1; off < 64; off <<= 1) {
    s0 += __shfl_xor(s0, off);
    s1 += __shfl_xor(s1, off);
    s2 += __shfl_xor(s2, off);
  }
  if (lane == 0) {
    out3[n * 3 + 0] = s0 + b[0];
    out3[n * 3 + 1] = s1 + b[1];
    out3[n * 3 + 2] = s2 + b[2];
  }
}

extern "C" void kernel_launch(void* const* d_in, const int* in_sizes, int n_in,
                              void* d_out, int out_size, void* d_ws, size_t ws_size,
                              hipStream_t stream) {
  const float* x         = (const float*)d_in[0];
  const float* edge_attr = (const float*)d_in[1];
  const int*   eidx      = (const int*)d_in[2];
  const float* lift_W    = (const float*)d_in[3];
  const float* lift_b    = (const float*)d_in[4];
  const float* Wl        = (const float*)d_in[5];
  const float* bl        = (const float*)d_in[6];
  const float* Wr        = (const float*)d_in[7];
  const float* br        = (const float*)d_in[8];
  const float* We        = (const float*)d_in[9];
  const float* att       = (const float*)d_in[10];
  const float* conv_b    = (const float*)d_in[11];
  const float* bn_g      = (const float*)d_in[12];
  const float* bn_b      = (const float*)d_in[13];
  const float* p1_W      = (const float*)d_in[14];
  const float* p1_b      = (const float*)d_in[15];
  const float* pbn1_g    = (const float*)d_in[16];
  const float* pbn1_b    = (const float*)d_in[17];
  const float* p2_W      = (const float*)d_in[18];
  const float* p2_b      = (const float*)d_in[19];
  const float* pbn2_g    = (const float*)d_in[20];
  const float* pbn2_b    = (const float*)d_in[21];
  const float* p3_W      = (const float*)d_in[22];
  const float* p3_b      = (const float*)d_in[23];
  const int* srcI = eidx;
  const int* dstI = eidx + Ee;

  char* wp = (char*)d_ws;
  auto carve = [&](size_t bytes) -> void* {
    void* p = (void*)wp;
    wp += (bytes + 255) & ~(size_t)255;
    return p;
  };
  float* ea     = (float*)carve((size_t)Ee * 9 * sizeof(float));
  f16*   h16    = (f16*)carve((size_t)Nn * 256 * sizeof(f16));
  f16*   w16t   = (f16*)carve((size_t)12 * 65536 * sizeof(f16));
  float* xl     = (float*)carve((size_t)Nn * 256 * sizeof(float));
  float* xr     = (float*)carve((size_t)Nn * 256 * sizeof(float));
  float* outb   = (float*)carve((size_t)Nn * 256 * sizeof(float));
  int*   deg    = (int*)carve((size_t)Nn * sizeof(int));
  int*   rowptr = (int*)carve((size_t)(Nn + 1) * sizeof(int));
  int*   cursor = (int*)carve((size_t)Nn * sizeof(int));
  int*   perm   = (int*)carve((size_t)Ee * sizeof(int));
  float* cstats = (float*)carve(32 * sizeof(float));
  float* bnsums = (float*)carve(512 * sizeof(float));

  hipMemsetAsync(cstats, 0, 32 * sizeof(float), stream);
  hipMemsetAsync(deg, 0, Nn * sizeof(int), stream);

  colstats_kernel<<<64, 256, 0, stream>>>(edge_attr, cstats);
  eanorm_kernel<<<(Ee * 9 + 255) / 256, 256, 0, stream>>>(edge_attr, cstats, ea);
  lift_kernel<<<Nn, 256, 0, stream>>>(x, lift_W, lift_b, h16);
  degree_kernel<<<(Ee + 255) / 256, 256, 0, stream>>>(dstI, deg);
  scan_kernel<<<1, 1024, 0, stream>>>(deg, rowptr, cursor);
  fill_kernel<<<(Ee + 255) / 256, 256, 0, stream>>>(dstI, cursor, perm);
  convert_kernel<<<dim3(256, 12), 256, 0, stream>>>(Wl, Wr, p1_W, p2_W, w16t);

  dim3 ggrid((Nn + 63) / 64, 4);
  for (int t = 0; t < Tt; ++t) {
    gemm16_kernel<<<ggrid, 256, 0, stream>>>(h16, w16t + (size_t)t * 65536, bl + t * 256, xl, Nn);
    gemm16_kernel<<<ggrid, 256, 0, stream>>>(h16, w16t + (size_t)(5 + t) * 65536, br + t * 256, xr, Nn);
    gat_kernel<<<(Nn + 3) / 4, 256, 0, stream>>>(xl, xr, ea, srcI, rowptr, perm,
                                                 We + t * 9 * 256, att + t * 256,
                                                 conv_b + t * 256, outb);
    hipMemsetAsync(bnsums, 0, 512 * sizeof(float), stream);
    bn_stats_kernel<<<64, 256, 0, stream>>>(outb, bnsums);
    bn_apply_kernel<<<Nn, 256, 0, stream>>>(outb, bnsums, bn_g + t * 256, bn_b + t * 256, h16, 0);
  }
  // projection head
  gemm16_kernel<<<ggrid, 256, 0, stream>>>(h16, w16t + (size_t)10 * 65536, p1_b, outb, Nn);
  hipMemsetAsync(bnsums, 0, 512 * sizeof(float), stream);
  bn_stats_kernel<<<64, 256, 0, stream>>>(outb, bnsums);
  bn_apply_kernel<<<Nn, 256, 0, stream>>>(outb, bnsums, pbn1_g, pbn1_b, h16, 1);

  gemm16_kernel<<<ggrid, 256, 0, stream>>>(h16, w16t + (size_t)11 * 65536, p2_b, outb, Nn);
  hipMemsetAsync(bnsums, 0, 512 * sizeof(float), stream);
  bn_stats_kernel<<<64, 256, 0, stream>>>(outb, bnsums);
  bn_apply_kernel<<<Nn, 256, 0, stream>>>(outb, bnsums, pbn2_g, pbn2_b, h16, 1);

  final_kernel<<<Nn, 64, 0, stream>>>(h16, p3_W, p3_b, (float*)d_out);
}

// Round 2
// 792.257 us; speedup vs baseline: 1.2212x; 1.2212x over previous
//
#include <hip/hip_runtime.h>

#define Nn 10000
#define Ee 160000
#define HID 256
#define EDIM 9
#define INDIM 10
#define Tt 5

typedef _Float16 f16;
typedef _Float16 f16x8 __attribute__((ext_vector_type(8)));
typedef _Float16 f16x4 __attribute__((ext_vector_type(4)));
typedef float f32x4 __attribute__((ext_vector_type(4)));

// ---------------- edge-attr column stats (mean / sumsq) ----------------
__global__ __launch_bounds__(256) void colstats_kernel(const float* __restrict__ in,
                                                       float* __restrict__ cs) {
  float s[9], s2[9];
#pragma unroll
  for (int k = 0; k < 9; ++k) { s[k] = 0.f; s2[k] = 0.f; }
  for (int i = blockIdx.x * blockDim.x + threadIdx.x; i < Ee; i += gridDim.x * blockDim.x) {
#pragma unroll
    for (int k = 0; k < 9; ++k) {
      float v = in[i * 9 + k];
      s[k] += v; s2[k] += v * v;
    }
  }
#pragma unroll
  for (int k = 0; k < 9; ++k) {
    for (int off = 1; off < 64; off <<= 1) {
      s[k] += __shfl_xor(s[k], off);
      s2[k] += __shfl_xor(s2[k], off);
    }
  }
  if ((threadIdx.x & 63) == 0) {
#pragma unroll
    for (int k = 0; k < 9; ++k) {
      atomicAdd(&cs[k], s[k]);
      atomicAdd(&cs[16 + k], s2[k]);
    }
  }
}

// ---------------- lift: h = relu(x @ lift_W + b), stored fp16 ----------------
__global__ __launch_bounds__(256) void lift_kernel(const float* __restrict__ x,
                                                   const float* __restrict__ W,
                                                   const float* __restrict__ b,
                                                   f16* __restrict__ hq) {
  __shared__ float xs[INDIM];
  int n = blockIdx.x, ch = threadIdx.x;
  if (ch < INDIM) xs[ch] = x[n * INDIM + ch];
  __syncthreads();
  float s = b[ch];
#pragma unroll
  for (int k = 0; k < INDIM; ++k) s += xs[k] * W[k * 256 + ch];
  hq[n * 256 + ch] = (f16)fmaxf(s, 0.f);
}

// ---------------- CSR build (by destination) ----------------
__global__ __launch_bounds__(256) void degree_kernel(const int* __restrict__ dst,
                                                     int* __restrict__ deg) {
  int e = blockIdx.x * 256 + threadIdx.x;
  if (e < Ee) atomicAdd(&deg[dst[e]], 1);
}

__global__ __launch_bounds__(1024) void scan_kernel(const int* __restrict__ deg,
                                                    int* __restrict__ rowptr,
                                                    int* __restrict__ cursor) {
  __shared__ int part[1024];
  int tid = threadIdx.x;
  const int CH = (Nn + 1023) / 1024;
  int start = tid * CH;
  int s = 0;
  for (int i = 0; i < CH; ++i) { int idx = start + i; if (idx < Nn) s += deg[idx]; }
  part[tid] = s;
  __syncthreads();
  for (int off = 1; off < 1024; off <<= 1) {
    int v = part[tid];
    int w = (tid >= off) ? part[tid - off] : 0;
    __syncthreads();
    part[tid] = v + w;
    __syncthreads();
  }
  int run = part[tid] - s;  // exclusive prefix
  for (int i = 0; i < CH; ++i) {
    int idx = start + i;
    if (idx < Nn) { rowptr[idx] = run; cursor[idx] = run; run += deg[idx]; }
  }
  if (tid == 0) rowptr[Nn] = Ee;
}

__global__ __launch_bounds__(256) void fill_kernel(const int* __restrict__ dst,
                                                   int* __restrict__ cursor,
                                                   int* __restrict__ perm) {
  int e = blockIdx.x * 256 + threadIdx.x;
  if (e < Ee) {
    int pos = atomicAdd(&cursor[dst[e]], 1);
    perm[pos] = e;
  }
}

// -------- permute src + normalized edge-attr into CSR order (stride 12, f4-aligned) ------
__global__ __launch_bounds__(256) void eaperm_kernel(const float* __restrict__ edge_attr,
                                                     const float* __restrict__ cs,
                                                     const int* __restrict__ perm,
                                                     const int* __restrict__ srcIn,
                                                     int* __restrict__ srcp,
                                                     float* __restrict__ eap) {
  int idx = blockIdx.x * 256 + threadIdx.x;
  if (idx >= Ee) return;
  int e = perm[idx];
  srcp[idx] = srcIn[e];
  const float* a = edge_attr + e * 9;
  float o[12];
#pragma unroll
  for (int k = 0; k < 9; ++k) {
    float mu = cs[k] * (1.f / Ee);
    float var = fmaxf(cs[16 + k] * (1.f / Ee) - mu * mu, 0.f);
    o[k] = (a[k] - mu) / (sqrtf(var) + 1e-8f);
  }
  o[9] = o[10] = o[11] = 0.f;
  float4 v0 = {o[0], o[1], o[2], o[3]};
  float4 v1 = {o[4], o[5], o[6], o[7]};
  float4 v2 = {o[8], o[9], o[10], o[11]};
  *(float4*)(eap + (size_t)idx * 12 + 0) = v0;
  *(float4*)(eap + (size_t)idx * 12 + 4) = v1;
  *(float4*)(eap + (size_t)idx * 12 + 8) = v2;
}

// ---------------- weight convert: fp32 [256k,256n] -> fp16 transposed ----------------
// slots 0..4: layer t -> [512 rows][256] (Wl^T rows 0-255, Wr^T rows 256-511) at t*131072
// slot 5: p1 [256][256] at 655360 ; slot 6: p2 at 720896
__global__ __launch_bounds__(256) void convert_kernel(const float* __restrict__ Wl,
                                                      const float* __restrict__ Wr,
                                                      const float* __restrict__ p1,
                                                      const float* __restrict__ p2,
                                                      f16* __restrict__ wt) {
  int nrow = blockIdx.x, s = blockIdx.y, k = threadIdx.x;
  const float* srcp; int n = nrow; size_t dst;
  if (s < 5) {
    dst = (size_t)s * 131072 + (size_t)nrow * 256 + k;
    if (nrow < 256) srcp = Wl + s * 65536;
    else { srcp = Wr + s * 65536; n = nrow - 256; }
  } else {
    if (nrow >= 256) return;
    dst = 655360 + (size_t)(s - 5) * 65536 + (size_t)nrow * 256 + k;
    srcp = (s == 5) ? p1 : p2;
  }
  wt[dst] = (f16)srcp[k * 256 + n];
}

__global__ __launch_bounds__(256) void prep_bias_kernel(const float* __restrict__ bl,
                                                        const float* __restrict__ br,
                                                        float* __restrict__ bc) {
  int idx = blockIdx.x * 256 + threadIdx.x;  // 2560
  if (idx >= 2560) return;
  int t = idx >> 9, c = idx & 511;
  bc[idx] = (c < 256) ? bl[t * 256 + c] : br[t * 256 + c - 256];
}

// ---------------- fp16 MFMA GEMM, full-K LDS staging, fp16 out ----------------
// C[M, OS(slice n0..n0+63)] = A[M,256] @ B^T + bias ; tile 64x64, 4 waves
__global__ __launch_bounds__(256) void gemm16_kernel(const f16* __restrict__ A,
                                                     const f16* __restrict__ BT,
                                                     const float* __restrict__ bias,
                                                     f16* __restrict__ out,
                                                     int M, int OS) {
  __shared__ __align__(16) f16 As[64][264];
  __shared__ __align__(16) f16 Bs[64][264];
  const int tid = threadIdx.x;
  const int wave = tid >> 6, lane = tid & 63;
  const int l15 = lane & 15, quad = lane >> 4;
  const int m0 = blockIdx.x * 64, n0 = blockIdx.y * 64;
  const int wm = (wave >> 1) * 32, wn = (wave & 1) * 32;
  // stage full 64x256 panels: 8 16B-chunks of A and B per thread, coalesced
#pragma unroll
  for (int i = 0; i < 8; ++i) {
    int c = tid + 256 * i;            // 0..2047
    int row = c >> 5, col = (c & 31) * 8;
    f16x8 av = {};
    int gm = m0 + row;
    if (gm < M) av = *(const f16x8*)(A + (size_t)gm * 256 + col);
    *(f16x8*)(&As[row][col]) = av;
    f16x8 bv = *(const f16x8*)(BT + (size_t)(n0 + row) * 256 + col);
    *(f16x8*)(&Bs[row][col]) = bv;
  }
  __syncthreads();
  f32x4 zero4 = {0.f, 0.f, 0.f, 0.f};
  f32x4 acc[2][2] = {{zero4, zero4}, {zero4, zero4}};
#pragma unroll
  for (int kk = 0; kk < 256; kk += 32) {
    f16x8 a0 = *(const f16x8*)(&As[wm + l15][kk + quad * 8]);
    f16x8 a1 = *(const f16x8*)(&As[wm + 16 + l15][kk + quad * 8]);
    f16x8 b0 = *(const f16x8*)(&Bs[wn + l15][kk + quad * 8]);
    f16x8 b1 = *(const f16x8*)(&Bs[wn + 16 + l15][kk + quad * 8]);
    acc[0][0] = __builtin_amdgcn_mfma_f32_16x16x32_f16(a0, b0, acc[0][0], 0, 0, 0);
    acc[0][1] = __builtin_amdgcn_mfma_f32_16x16x32_f16(a0, b1, acc[0][1], 0, 0, 0);
    acc[1][0] = __builtin_amdgcn_mfma_f32_16x16x32_f16(a1, b0, acc[1][0], 0, 0, 0);
    acc[1][1] = __builtin_amdgcn_mfma_f32_16x16x32_f16(a1, b1, acc[1][1], 0, 0, 0);
  }
  // epilogue: bias add, fp16 via LDS transpose for coalesced 16B stores
  __syncthreads();
  f16* Cs = (f16*)&As[0][0];  // 64 x 72 tile
#pragma unroll
  for (int ni = 0; ni < 2; ++ni) {
    int nl = wn + ni * 16 + l15;
    float bv = bias[n0 + nl];
#pragma unroll
    for (int mi = 0; mi < 2; ++mi)
#pragma unroll
      for (int r = 0; r < 4; ++r)
        Cs[(wm + mi * 16 + quad * 4 + r) * 72 + nl] = (f16)(acc[mi][ni][r] + bv);
  }
  __syncthreads();
  {
    int row = tid >> 2, c4 = (tid & 3) * 16;
    int gm = m0 + row;
    if (gm < M) {
      f16x8 v0 = *(const f16x8*)(&Cs[row * 72 + c4]);
      f16x8 v1 = *(const f16x8*)(&Cs[row * 72 + c4 + 8]);
      *(f16x8*)(out + (size_t)gm * OS + n0 + c4) = v0;
      *(f16x8*)(out + (size_t)gm * OS + n0 + c4 + 8) = v1;
    }
  }
}

// ---------------- GATv2: wave/node, batch-4 edges, online softmax ----------------
__global__ __launch_bounds__(256) void gat_kernel(const f16* __restrict__ hxlr,
                                                  const float* __restrict__ eap,
                                                  const int* __restrict__ srcp,
                                                  const int* __restrict__ rowptr,
                                                  const float* __restrict__ We_t,
                                                  const float* __restrict__ att_t,
                                                  const float* __restrict__ cb_t,
                                                  f16* __restrict__ outb) {
  int wave = threadIdx.x >> 6, lane = threadIdx.x & 63;
  int i = blockIdx.x * 4 + wave;
  if (i >= Nn) return;
  int ch = lane * 4;  // lane owns flat channels [4*lane, 4*lane+4); head = lane>>3
  float we[9][4];
#pragma unroll
  for (int k = 0; k < 9; ++k) {
    float4 w4 = *(const float4*)(We_t + k * 256 + ch);
    we[k][0] = w4.x; we[k][1] = w4.y; we[k][2] = w4.z; we[k][3] = w4.w;
  }
  float4 a4 = *(const float4*)(att_t + ch);
  float att[4] = {a4.x, a4.y, a4.z, a4.w};
  f16x4 xr4 = *(const f16x4*)(hxlr + (size_t)i * 512 + 256 + ch);
  float xri[4] = {(float)xr4[0], (float)xr4[1], (float)xr4[2], (float)xr4[3]};
  float m = -INFINITY, l = 0.f;
  float acc[4] = {0.f, 0.f, 0.f, 0.f};
  int r0 = rowptr[i], r1 = rowptr[i + 1];
  for (int base = r0; base < r1; base += 4) {
    int cnt = r1 - base;  // >=1; valid lanes b < cnt
    int jj[4];
#pragma unroll
    for (int b = 0; b < 4; ++b) {
      int bb = b < cnt ? b : cnt - 1;
      jj[b] = srcp[base + bb];
    }
    float xlv[4][4];
#pragma unroll
    for (int b = 0; b < 4; ++b) {
      f16x4 v4 = *(const f16x4*)(hxlr + (size_t)jj[b] * 512 + ch);
      xlv[b][0] = (float)v4[0]; xlv[b][1] = (float)v4[1];
      xlv[b][2] = (float)v4[2]; xlv[b][3] = (float)v4[3];
    }
    float sp[4];
#pragma unroll
    for (int b = 0; b < 4; ++b) {
      int bb = b < cnt ? b : cnt - 1;
      const float* ep = eap + (size_t)(base + bb) * 12;
      float4 e0 = *(const float4*)ep;
      float4 e1 = *(const float4*)(ep + 4);
      float e8 = ep[8];
      float v[4];
#pragma unroll
      for (int c = 0; c < 4; ++c) v[c] = xlv[b][c] + xri[c];
#pragma unroll
      for (int c = 0; c < 4; ++c) {
        v[c] += e0.x * we[0][c] + e0.y * we[1][c] + e0.z * we[2][c] + e0.w * we[3][c];
        v[c] += e1.x * we[4][c] + e1.y * we[5][c] + e1.z * we[6][c] + e1.w * we[7][c];
        v[c] += e8 * we[8][c];
      }
      float s = 0.f;
#pragma unroll
      for (int c = 0; c < 4; ++c) {
        float vv = v[c];
        vv = vv > 0.f ? vv : 0.2f * vv;  // leaky_relu 0.2
        s += att[c] * vv;
      }
      sp[b] = s;
    }
#pragma unroll
    for (int b = 0; b < 4; ++b) {
      sp[b] += __shfl_xor(sp[b], 1);
      sp[b] += __shfl_xor(sp[b], 2);
      sp[b] += __shfl_xor(sp[b], 4);
    }
#pragma unroll
    for (int b = 0; b < 4; ++b) if (b >= cnt) sp[b] = -INFINITY;
    // batch max then single rescale
    float bm = fmaxf(fmaxf(sp[0], sp[1]), fmaxf(sp[2], sp[3]));
    float nm = fmaxf(m, bm);
    float sc = __expf(m - nm);  // exp(-inf)=0 on first batch
    float p[4];
#pragma unroll
    for (int b = 0; b < 4; ++b) p[b] = __expf(sp[b] - nm);
    l = l * sc + p[0] + p[1] + p[2] + p[3];
#pragma unroll
    for (int c = 0; c < 4; ++c)
      acc[c] = acc[c] * sc + p[0] * xlv[0][c] + p[1] * xlv[1][c] + p[2] * xlv[2][c] + p[3] * xlv[3][c];
    m = nm;
  }
  float4 cb4 = *(const float4*)(cb_t + ch);
  float inv = 1.f / (l + 1e-16f);  // empty node -> bias only (matches ref)
  f16x4 o;
  o[0] = (f16)(acc[0] * inv + cb4.x);
  o[1] = (f16)(acc[1] * inv + cb4.y);
  o[2] = (f16)(acc[2] * inv + cb4.z);
  o[3] = (f16)(acc[3] * inv + cb4.w);
  *(f16x4*)(outb + (size_t)i * 256 + ch) = o;
}

// ---------------- BatchNorm batch-stats + apply(+act), fp16 I/O ----------------
__global__ __launch_bounds__(256) void bn_stats_kernel(const f16* __restrict__ v,
                                                       float* __restrict__ sums) {
  int ch = threadIdx.x;
  float s = 0.f, s2 = 0.f;
  for (int n = blockIdx.x; n < Nn; n += gridDim.x) {
    float x = (float)v[(size_t)n * 256 + ch];
    s += x; s2 += x * x;
  }
  atomicAdd(&sums[ch], s);
  atomicAdd(&sums[256 + ch], s2);
}

__global__ __launch_bounds__(256) void bn_apply_kernel(const f16* __restrict__ v,
                                                       const float* __restrict__ sums,
                                                       const float* __restrict__ gamma,
                                                       const float* __restrict__ beta,
                                                       f16* __restrict__ hq, int act) {
  int idx = blockIdx.x * 256 + threadIdx.x;  // handles 4 f16
  size_t base = (size_t)idx * 4;
  int ch = (int)(base & 255);
  f16x4 in4 = *(const f16x4*)(v + base);
  float4 su = *(const float4*)(sums + ch);
  float4 sq = *(const float4*)(sums + 256 + ch);
  float4 g4 = *(const float4*)(gamma + ch);
  float4 b4 = *(const float4*)(beta + ch);
  float su_[4] = {su.x, su.y, su.z, su.w};
  float sq_[4] = {sq.x, sq.y, sq.z, sq.w};
  float g_[4] = {g4.x, g4.y, g4.z, g4.w};
  float b_[4] = {b4.x, b4.y, b4.z, b4.w};
  f16x4 o;
#pragma unroll
  for (int c = 0; c < 4; ++c) {
    float mu = su_[c] * (1.f / Nn);
    float var = fmaxf(sq_[c] * (1.f / Nn) - mu * mu, 0.f);  // biased var
    float inv = rsqrtf(var + 1e-5f);
    float y = g_[c] * ((float)in4[c] - mu) * inv + b_[c];
    if (act == 0) y = y > 0.f ? y : (__expf(y) - 1.f);  // ELU
    else y = fmaxf(y, 0.f);                             // ReLU
    o[c] = (f16)y;
  }
  *(f16x4*)(hq + base) = o;
}

// ---------------- final 256 -> 3 projection ----------------
__global__ __launch_bounds__(256) void final_kernel(const f16* __restrict__ hq,
                                                    const float* __restrict__ W,
                                                    const float* __restrict__ b,
                                                    float* __restrict__ out3) {
  int wave = threadIdx.x >> 6, lane = threadIdx.x & 63;
  int n = blockIdx.x * 4 + wave;
  if (n >= Nn) return;
  int ch = lane * 4;
  f16x4 h4 = *(const f16x4*)(hq + (size_t)n * 256 + ch);
  float s0 = 0.f, s1 = 0.f, s2 = 0.f;
#pragma unroll
  for (int c2 = 0; c2 < 4; ++c2) {
    float h = (float)h4[c2];
    const float* w = W + (ch + c2) * 3;
    s0 += h * w[0]; s1 += h * w[1]; s2 += h * w[2];
  }
  for (int off = 1; off < 64; off <<= 1) {
    s0 += __shfl_xor(s0, off);
    s1 += __shfl_xor(s1, off);
    s2 += __shfl_xor(s2, off);
  }
  if (lane == 0) {
    out3[n * 3 + 0] = s0 + b[0];
    out3[n * 3 + 1] = s1 + b[1];
    out3[n * 3 + 2] = s2 + b[2];
  }
}

extern "C" void kernel_launch(void* const* d_in, const int* in_sizes, int n_in,
                              void* d_out, int out_size, void* d_ws, size_t ws_size,
                              hipStream_t stream) {
  const float* x         = (const float*)d_in[0];
  const float* edge_attr = (const float*)d_in[1];
  const int*   eidx      = (const int*)d_in[2];
  const float* lift_W    = (const float*)d_in[3];
  const float* lift_b    = (const float*)d_in[4];
  const float* Wl        = (const float*)d_in[5];
  const float* bl        = (const float*)d_in[6];
  const float* Wr        = (const float*)d_in[7];
  const float* br        = (const float*)d_in[8];
  const float* We        = (const float*)d_in[9];
  const float* att       = (const float*)d_in[10];
  const float* conv_b    = (const float*)d_in[11];
  const float* bn_g      = (const float*)d_in[12];
  const float* bn_b      = (const float*)d_in[13];
  const float* p1_W      = (const float*)d_in[14];
  const float* p1_b      = (const float*)d_in[15];
  const float* pbn1_g    = (const float*)d_in[16];
  const float* pbn1_b    = (const float*)d_in[17];
  const float* p2_W      = (const float*)d_in[18];
  const float* p2_b      = (const float*)d_in[19];
  const float* pbn2_g    = (const float*)d_in[20];
  const float* pbn2_b    = (const float*)d_in[21];
  const float* p3_W      = (const float*)d_in[22];
  const float* p3_b      = (const float*)d_in[23];
  const int* srcI = eidx;
  const int* dstI = eidx + Ee;

  char* wp = (char*)d_ws;
  auto carve = [&](size_t bytes) -> void* {
    void* p = (void*)wp;
    wp += (bytes + 255) & ~(size_t)255;
    return p;
  };
  float* eap    = (float*)carve((size_t)Ee * 12 * sizeof(float));
  f16*   h16    = (f16*)carve((size_t)Nn * 256 * sizeof(f16));
  f16*   w16t   = (f16*)carve((size_t)786432 * sizeof(f16));
  float* biascat= (float*)carve((size_t)2560 * sizeof(float));
  f16*   hxlr   = (f16*)carve((size_t)Nn * 512 * sizeof(f16));
  f16*   outb16 = (f16*)carve((size_t)Nn * 256 * sizeof(f16));
  int*   deg    = (int*)carve((size_t)Nn * sizeof(int));
  int*   rowptr = (int*)carve((size_t)(Nn + 1) * sizeof(int));
  int*   cursor = (int*)carve((size_t)Nn * sizeof(int));
  int*   perm   = (int*)carve((size_t)Ee * sizeof(int));
  int*   srcp   = (int*)carve((size_t)Ee * sizeof(int));
  float* cstats = (float*)carve(32 * sizeof(float));
  float* bnsums = (float*)carve(512 * sizeof(float));

  hipMemsetAsync(cstats, 0, 32 * sizeof(float), stream);
  hipMemsetAsync(deg, 0, Nn * sizeof(int), stream);

  colstats_kernel<<<64, 256, 0, stream>>>(edge_attr, cstats);
  lift_kernel<<<Nn, 256, 0, stream>>>(x, lift_W, lift_b, h16);
  degree_kernel<<<(Ee + 255) / 256, 256, 0, stream>>>(dstI, deg);
  scan_kernel<<<1, 1024, 0, stream>>>(deg, rowptr, cursor);
  fill_kernel<<<(Ee + 255) / 256, 256, 0, stream>>>(dstI, cursor, perm);
  eaperm_kernel<<<(Ee + 255) / 256, 256, 0, stream>>>(edge_attr, cstats, perm, srcI, srcp, eap);
  convert_kernel<<<dim3(512, 7), 256, 0, stream>>>(Wl, Wr, p1_W, p2_W, w16t);
  prep_bias_kernel<<<10, 256, 0, stream>>>(bl, br, biascat);

  const int MB = (Nn + 63) / 64;  // 157
  for (int t = 0; t < Tt; ++t) {
    gemm16_kernel<<<dim3(MB, 8), 256, 0, stream>>>(h16, w16t + (size_t)t * 131072,
                                                   biascat + t * 512, hxlr, Nn, 512);
    gat_kernel<<<(Nn + 3) / 4, 256, 0, stream>>>(hxlr, eap, srcp, rowptr,
                                                 We + t * 9 * 256, att + t * 256,
                                                 conv_b + t * 256, outb16);
    hipMemsetAsync(bnsums, 0, 512 * sizeof(float), stream);
    bn_stats_kernel<<<256, 256, 0, stream>>>(outb16, bnsums);
    bn_apply_kernel<<<2500, 256, 0, stream>>>(outb16, bnsums, bn_g + t * 256, bn_b + t * 256, h16, 0);
  }
  // projection head
  gemm16_kernel<<<dim3(MB, 4), 256, 0, stream>>>(h16, w16t + 655360, p1_b, outb16, Nn, 256);
  hipMemsetAsync(bnsums, 0, 512 * sizeof(float), stream);
  bn_stats_kernel<<<256, 256, 0, stream>>>(outb16, bnsums);
  bn_apply_kernel<<<2500, 256, 0, stream>>>(outb16, bnsums, pbn1_g, pbn1_b, h16, 1);

  gemm16_kernel<<<dim3(MB, 4), 256, 0, stream>>>(h16, w16t + 720896, p2_b, outb16, Nn, 256);
  hipMemsetAsync(bnsums, 0, 512 * sizeof(float), stream);
  bn_stats_kernel<<<256, 256, 0, stream>>>(outb16, bnsums);
  bn_apply_kernel<<<2500, 256, 0, stream>>>(outb16, bnsums, pbn2_g, pbn2_b, h16, 1);

  final_kernel<<<2500, 256, 0, stream>>>(h16, p3_W, p3_b, (float*)d_out);
}